// Round 4
// baseline (13580.727 us; speedup 1.0000x reference)
//
#include <hip/hip_runtime.h>
#include <hip/hip_bf16.h>

#define NEG 0.01f
#define BN_EPS 1e-5f

typedef __hip_bfloat16 bf16;
typedef __attribute__((ext_vector_type(8))) short short8;
typedef __attribute__((ext_vector_type(16))) float f32x16;
typedef __attribute__((ext_vector_type(4))) float f32x4;

__device__ inline float bits2f(short s) {
    return __uint_as_float(((unsigned)(unsigned short)s) << 16);
}
__device__ inline short f2bits(float f) {
    union { bf16 h; short s; } u;
    u.h = __float2bfloat16(f);
    return u.s;
}

// ---------------- small kernels ----------------

// stats slot: [sum(64), sumsq(64), mean(64), rstd(64)] = 256 floats
__global__ void finalize_k(float* stats, int slotA, int slotB, float inv_n) {
    int slot = (blockIdx.x == 0) ? slotA : slotB;
    float* s = stats + (size_t)slot * 256;
    int c = threadIdx.x;  // 64 threads
    float m = s[c] * inv_n;
    float v = s[64 + c] * inv_n - m * m;
    s[128 + c] = m;
    s[192 + c] = rsqrtf(v + BN_EPS);
}

__global__ void bn2_add(const bf16* __restrict__ a, const float* __restrict__ ma,
                        const float* __restrict__ ra, const bf16* __restrict__ b,
                        const float* __restrict__ mb, const float* __restrict__ rb,
                        bf16* __restrict__ out, int n_elem) {
    int i = blockIdx.x * blockDim.x + threadIdx.x;
    if (i >= n_elem) return;
    int c = i & 63;
    float va = ((float)a[i] - ma[c]) * ra[c];
    va = va > 0.f ? va : NEG * va;
    float vb = ((float)b[i] - mb[c]) * rb[c];
    vb = vb > 0.f ? vb : NEG * vb;
    out[i] = __float2bfloat16(va + vb);
}

__global__ void cvt_f32_bf16_k(const float* __restrict__ x, bf16* __restrict__ y, int n) {
    int i = blockIdx.x * blockDim.x + threadIdx.x;
    if (i < n) y[i] = __float2bfloat16(x[i]);
}

// ---------------- weight pack (center taps + down parts) ----------------
// layout per entry: [s][c][lane][j] : elem j of lane l at (s,c) =
//   W[s*16 + (l>>5)*8 + j][c*32 + (l&31)]   (B-fragment for 32x32x16 bf16)
struct PackEnt { const float* src; bf16* dst; int ns; };
struct PackArgs { PackEnt e[15]; };

__global__ void pack_w_k(PackArgs pa) {
    PackEnt E = pa.e[blockIdx.y];
    int total = E.ns * 1024;
    for (int i = blockIdx.x * blockDim.x + threadIdx.x; i < total;
         i += gridDim.x * blockDim.x) {
        int j = i & 7, lane = (i >> 3) & 63, c = (i >> 9) & 1;
        int s = i >> 10;
        int krow = s * 16 + ((lane >> 5) << 3) + j;
        int col = c * 32 + (lane & 31);
        E.dst[i] = __float2bfloat16(E.src[(size_t)krow * 64 + col]);
    }
}

// ---------------- pair-list compaction ----------------
struct MapDesc {
    const int* nbr; int2* list; int* cnt;
    int n_out; int K; int center; int n_in; int cap;
};
struct MapArgs { MapDesc m[7]; };

__global__ void compact_k(MapArgs ma) {
    MapDesc d = ma.m[blockIdx.y];
    int total = d.K * d.n_out;
    for (int e = blockIdx.x * blockDim.x + threadIdx.x; e < total;
         e += gridDim.x * blockDim.x) {
        int k = e / d.n_out;
        int n = e - k * d.n_out;
        int idx = d.nbr[e];
        if (k != d.center && idx < d.n_in) {
            int pos = atomicAdd(d.cnt, 1);
            if (pos < d.cap) d.list[pos] = make_int2(n | (k << 20), idx);
        }
    }
}

// ---------------- sparse correction: one wave per pair ----------------
// corr[n,:] += bnact?(fin[idx,:]) @ W[k]   (W raw fp32 [K][CIN][64])
template <int CIN, bool BN>
__global__ __launch_bounds__(256) void pairs_k(
    const bf16* __restrict__ fin, const int2* __restrict__ list,
    const int* __restrict__ cnt, int cap, const float* __restrict__ W,
    const float* __restrict__ bn_m, const float* __restrict__ bn_r,
    float* __restrict__ corr) {
    const int lane = threadIdx.x & 63;
    const int wid = blockIdx.x * (blockDim.x >> 6) + (threadIdx.x >> 6);
    const int nw = gridDim.x * (blockDim.x >> 6);
    int count = *cnt;
    if (count > cap) count = cap;
    for (int p = wid; p < count; p += nw) {
        int2 e = list[p];
        int n = e.x & 0xFFFFF;
        int k = e.x >> 20;
        int idx = e.y;
        float fv = 0.f;
        if (lane < CIN) {
            fv = (float)fin[(size_t)idx * CIN + lane];
            if (BN) {
                fv = (fv - bn_m[lane]) * bn_r[lane];
                fv = fv > 0.f ? fv : NEG * fv;
            }
        }
        const float* wk = W + (size_t)k * CIN * 64 + lane;
        float acc = 0.f;
        #pragma unroll
        for (int j = 0; j < CIN; ++j)
            acc = fmaf(__shfl(fv, j), wk[(size_t)j * 64], acc);
        atomicAdd(&corr[(size_t)n * 64 + lane], acc);
    }
}

// ---------------- dense center GEMM (streaming, MFMA) ----------------
// out[n,:] = bnact?(fin[n,:]) @ Wc + corr[n,:]; optional stat accumulation.
// A[m=lane&31][k=(lane>>5)*8+j], C/D: col=lane&31, row=(i&3)+8*(i>>2)+4*(lane>>5)
template <int NS, bool BN, bool STAT>
__global__ __launch_bounds__(256) void dense_k(
    const bf16* __restrict__ fin, const bf16* __restrict__ Wc,
    const float* __restrict__ corr, const float* __restrict__ bn_m,
    const float* __restrict__ bn_r, bf16* __restrict__ out,
    float* __restrict__ stat, int n_out) {
    const int CIN = NS * 16;
    const int lane = threadIdx.x & 63;
    const int col = lane & 31;
    const int q = lane >> 5;
    const int wid = blockIdx.x * (blockDim.x >> 6) + (threadIdx.x >> 6);
    const int nw = gridDim.x * (blockDim.x >> 6);
    const int ntiles = (n_out + 31) >> 5;

    float ssum0 = 0.f, ssq0 = 0.f, ssum1 = 0.f, ssq1 = 0.f;

    for (int tile = wid; tile < ntiles; tile += nw) {
        const int rbase = tile << 5;
        const int r = rbase + col;
        const bool rowok = r < n_out;

        short8 a[NS];
        const bf16* src = fin + (size_t)r * CIN + q * 8;
        #pragma unroll
        for (int s = 0; s < NS; ++s) {
            if (rowok) a[s] = *(const short8*)(src + s * 16);
            else { short8 z = {0,0,0,0,0,0,0,0}; a[s] = z; }
        }
        if (BN) {
            #pragma unroll
            for (int s = 0; s < NS; ++s) {
                int chb = s * 16 + q * 8;
                f32x4 m0 = *(const f32x4*)(bn_m + chb);
                f32x4 m1 = *(const f32x4*)(bn_m + chb + 4);
                f32x4 r0 = *(const f32x4*)(bn_r + chb);
                f32x4 r1 = *(const f32x4*)(bn_r + chb + 4);
                #pragma unroll
                for (int j = 0; j < 8; ++j) {
                    float mm = (j < 4) ? m0[j & 3] : m1[j & 3];
                    float rr = (j < 4) ? r0[j & 3] : r1[j & 3];
                    float fe = (bits2f(a[s][j]) - mm) * rr;
                    fe = fe > 0.f ? fe : NEG * fe;
                    a[s][j] = f2bits(fe);
                }
            }
        }

        f32x16 acc0, acc1;
        #pragma unroll
        for (int i = 0; i < 16; ++i) { acc0[i] = 0.f; acc1[i] = 0.f; }
        const short8* wp = (const short8*)Wc + lane;
        #pragma unroll
        for (int s = 0; s < NS; ++s) {
            short8 b0 = wp[(s * 2 + 0) * 64];
            short8 b1 = wp[(s * 2 + 1) * 64];
            acc0 = __builtin_amdgcn_mfma_f32_32x32x16_bf16(a[s], b0, acc0, 0, 0, 0);
            acc1 = __builtin_amdgcn_mfma_f32_32x32x16_bf16(a[s], b1, acc1, 0, 0, 0);
        }

        #pragma unroll
        for (int i = 0; i < 16; ++i) {
            int row = (i & 3) + 8 * (i >> 2) + 4 * q;
            int gr = rbase + row;
            if (gr < n_out) {
                float v0 = acc0[i] + corr[(size_t)gr * 64 + col];
                float v1 = acc1[i] + corr[(size_t)gr * 64 + 32 + col];
                out[(size_t)gr * 64 + col] = __float2bfloat16(v0);
                out[(size_t)gr * 64 + 32 + col] = __float2bfloat16(v1);
                if (STAT) { ssum0 += v0; ssq0 += v0 * v0; ssum1 += v1; ssq1 += v1 * v1; }
            }
        }
    }
    if (STAT) {
        atomicAdd(&stat[col], ssum0);
        atomicAdd(&stat[32 + col], ssum1);
        atomicAdd(&stat[64 + col], ssq0);
        atomicAdd(&stat[96 + col], ssq1);
    }
}

// ---------------- fused down-projection ----------------
// out(fp32) = x1@W1 + x2@W2 + x3@W3  (each 64x64, packed)
__global__ __launch_bounds__(256) void down_k(
    const bf16* __restrict__ x1, const bf16* __restrict__ x2,
    const bf16* __restrict__ x3, const bf16* __restrict__ W1,
    const bf16* __restrict__ W2, const bf16* __restrict__ W3,
    float* __restrict__ out, int m) {
    const int lane = threadIdx.x & 63;
    const int col = lane & 31;
    const int q = lane >> 5;
    const int wid = blockIdx.x * (blockDim.x >> 6) + (threadIdx.x >> 6);
    const int nw = gridDim.x * (blockDim.x >> 6);
    const int ntiles = (m + 31) >> 5;

    for (int tile = wid; tile < ntiles; tile += nw) {
        const int rbase = tile << 5;
        const int r = rbase + col;
        const bool rowok = r < m;

        f32x16 acc0, acc1;
        #pragma unroll
        for (int i = 0; i < 16; ++i) { acc0[i] = 0.f; acc1[i] = 0.f; }

        const bf16* xs[3] = {x1, x2, x3};
        const bf16* ws[3] = {W1, W2, W3};
        #pragma unroll
        for (int t = 0; t < 3; ++t) {
            const bf16* src = xs[t] + (size_t)r * 64 + q * 8;
            const short8* wp = (const short8*)ws[t] + lane;
            #pragma unroll
            for (int s = 0; s < 4; ++s) {
                short8 a;
                if (rowok) a = *(const short8*)(src + s * 16);
                else { short8 z = {0,0,0,0,0,0,0,0}; a = z; }
                short8 b0 = wp[(s * 2 + 0) * 64];
                short8 b1 = wp[(s * 2 + 1) * 64];
                acc0 = __builtin_amdgcn_mfma_f32_32x32x16_bf16(a, b0, acc0, 0, 0, 0);
                acc1 = __builtin_amdgcn_mfma_f32_32x32x16_bf16(a, b1, acc1, 0, 0, 0);
            }
        }
        #pragma unroll
        for (int i = 0; i < 16; ++i) {
            int row = (i & 3) + 8 * (i >> 2) + 4 * q;
            int gr = rbase + row;
            if (gr < m) {
                out[(size_t)gr * 64 + col] = acc0[i];
                out[(size_t)gr * 64 + 32 + col] = acc1[i];
            }
        }
    }
}

// ---------------- host ----------------

extern "C" void kernel_launch(void* const* d_in, const int* in_sizes, int n_in_,
                              void* d_out, int out_size, void* d_ws,
                              size_t ws_size, hipStream_t stream) {
    const float* feats = (const float*)d_in[0];
    const float* Wraw[13] = {
        (const float*)d_in[1], (const float*)d_in[3],   // b1 w1(c1), w2(c2)  CIN32
        (const float*)d_in[2], (const float*)d_in[4],   // b1 w12(c3), w22(c4)
        (const float*)d_in[6], (const float*)d_in[8],   // b2 w1, w2
        (const float*)d_in[7], (const float*)d_in[9],   // b2 w12, w22
        (const float*)d_in[10], (const float*)d_in[12], // b3 w1, w2
        (const float*)d_in[11], (const float*)d_in[13], // b3 w12, w22
        (const float*)d_in[5],                           // pool (raw only)
    };
    const float* down_w = (const float*)d_in[14];
    const int* nA1 = (const int*)d_in[15];
    const int* nB1 = (const int*)d_in[16];
    const int* pnbr = (const int*)d_in[17];
    const int* nA2 = (const int*)d_in[18];
    const int* nB2 = (const int*)d_in[19];
    const int* nA3 = (const int*)d_in[20];
    const int* nB3 = (const int*)d_in[21];

    const int N = in_sizes[0] / 32;
    const int M = in_sizes[17] / 27;
    const size_t MX = (size_t)(N > M ? N : M);

    // ---- workspace layout ----
    bf16* A = (bf16*)d_ws;
    bf16* B = A + MX * 64;
    bf16* C = B + MX * 64;
    bf16* D = C + MX * 64;
    bf16* E = D + MX * 64;
    bf16* FB = E + MX * 64;           // feats bf16, N x 32
    bf16* WP = FB + (size_t)N * 32;   // packed centers + downs
    // pack entries: 0..11 subm centers (exec order), 12..14 down parts
    int nss[15] = {2, 2, 4, 4, 4, 4, 4, 4, 4, 4, 4, 4, 4, 4, 4};
    bf16* Wp[15];
    {
        size_t off = 0;
        for (int i = 0; i < 15; ++i) { Wp[i] = WP + off; off += (size_t)nss[i] * 1024; }
    }
    size_t wp_elems = 0;
    for (int i = 0; i < 15; ++i) wp_elems += (size_t)nss[i] * 1024;
    // lists (int2, 8B aligned — all preceding sizes are multiples of 8B)
    int2* LST = (int2*)(WP + wp_elems);
    int caps[7] = {N, N, 8 * N, M, M, M, M};   // nA1,nB1,pool,nA2,nB2,nA3,nB3
    int2* lst[7];
    {
        size_t off = 0;
        for (int i = 0; i < 7; ++i) { lst[i] = LST + off; off += (size_t)caps[i]; }
    }
    size_t lst_total = 0;
    for (int i = 0; i < 7; ++i) lst_total += (size_t)caps[i];
    float* ST = (float*)(LST + lst_total);    // 12 slots x 256
    int* CNT = (int*)(ST + 12 * 256);         // 7 counters (+pad)

    float* CORR = (float*)d_out;              // fp32 scratch until final down_k
    auto S = [&](int i) { return ST + (size_t)i * 256; };

    // ---- prep ----
    hipMemsetAsync(ST, 0, (12 * 256) * sizeof(float) + 8 * sizeof(int), stream);
    {
        PackArgs pa;
        // centers: subm weight W[k=4] starts at 4*CIN*64 floats
        int cins[12] = {32, 32, 64, 64, 64, 64, 64, 64, 64, 64, 64, 64};
        for (int i = 0; i < 12; ++i)
            pa.e[i] = {Wraw[i] + (size_t)4 * cins[i] * 64, Wp[i], nss[i]};
        for (int t = 0; t < 3; ++t)
            pa.e[12 + t] = {down_w + (size_t)t * 64 * 64, Wp[12 + t], 4};
        pack_w_k<<<dim3(16, 15), 256, 0, stream>>>(pa);
    }
    cvt_f32_bf16_k<<<(N * 32 + 255) / 256, 256, 0, stream>>>(feats, FB, N * 32);
    {
        MapArgs ma;
        const int* nbrs[7] = {nA1, nB1, pnbr, nA2, nB2, nA3, nB3};
        int nouts[7] = {N, N, M, M, M, M, M};
        int Ks[7] = {9, 9, 27, 9, 9, 9, 9};
        int ctr[7] = {4, 4, -1, 4, 4, 4, 4};
        int nins[7] = {N, N, N, M, M, M, M};
        for (int i = 0; i < 7; ++i)
            ma.m[i] = {nbrs[i], lst[i], CNT + i, nouts[i], Ks[i], ctr[i], nins[i], caps[i]};
        compact_k<<<dim3(2048, 7), 256, 0, stream>>>(ma);
    }

    const float invN = 1.f / (float)N, invM = 1.f / (float)M;
    const int neN = N * 64, neM = M * 64;
    const int gN = ((((N + 31) >> 5) + 3) >> 2), gM = ((((M + 31) >> 5) + 3) >> 2);
    const int eN = (neN + 255) / 256, eM = (neM + 255) / 256;
    const size_t zbN = (size_t)N * 64 * 4, zbM = (size_t)M * 64 * 4;
    const int PG = 512;  // pairs grid for subm maps

    // conv helper macro-ish sequences (explicit for clarity)
    // ---- block 1 @ N (CIN FB=32 for c1/c2) ----
    hipMemsetAsync(CORR, 0, zbN, stream);
    pairs_k<32, false><<<PG, 256, 0, stream>>>(FB, lst[0], CNT + 0, caps[0], Wraw[0], nullptr, nullptr, CORR);
    dense_k<2, false, true><<<gN, 256, 0, stream>>>(FB, Wp[0], CORR, nullptr, nullptr, A, S(0), N);
    hipMemsetAsync(CORR, 0, zbN, stream);
    pairs_k<32, false><<<PG, 256, 0, stream>>>(FB, lst[1], CNT + 1, caps[1], Wraw[1], nullptr, nullptr, CORR);
    dense_k<2, false, true><<<gN, 256, 0, stream>>>(FB, Wp[1], CORR, nullptr, nullptr, B, S(2), N);
    finalize_k<<<2, 64, 0, stream>>>(ST, 0, 2, invN);
    hipMemsetAsync(CORR, 0, zbN, stream);
    pairs_k<64, true><<<PG, 256, 0, stream>>>(A, lst[1], CNT + 1, caps[1], Wraw[2], S(0) + 128, S(0) + 192, CORR);
    dense_k<4, true, true><<<gN, 256, 0, stream>>>(A, Wp[2], CORR, S(0) + 128, S(0) + 192, C, S(1), N);
    hipMemsetAsync(CORR, 0, zbN, stream);
    pairs_k<64, true><<<PG, 256, 0, stream>>>(B, lst[0], CNT + 0, caps[0], Wraw[3], S(2) + 128, S(2) + 192, CORR);
    dense_k<4, true, true><<<gN, 256, 0, stream>>>(B, Wp[3], CORR, S(2) + 128, S(2) + 192, A, S(3), N);
    finalize_k<<<2, 64, 0, stream>>>(ST, 1, 3, invN);
    bn2_add<<<eN, 256, 0, stream>>>(C, S(1) + 128, S(1) + 192, A, S(3) + 128, S(3) + 192, B, neN);
    // XP = B (N x 64)

    // ---- pool (pairs only, 27 taps) -> X1 = D ----
    hipMemsetAsync(CORR, 0, zbM, stream);
    pairs_k<64, false><<<2048, 256, 0, stream>>>(B, lst[2], CNT + 2, caps[2], Wraw[12], nullptr, nullptr, CORR);
    cvt_f32_bf16_k<<<eM, 256, 0, stream>>>(CORR, D, neM);

    // ---- block 2 @ M, fin = D ----
    hipMemsetAsync(CORR, 0, zbM, stream);
    pairs_k<64, false><<<PG, 256, 0, stream>>>(D, lst[3], CNT + 3, caps[3], Wraw[4], nullptr, nullptr, CORR);
    dense_k<4, false, true><<<gM, 256, 0, stream>>>(D, Wp[4], CORR, nullptr, nullptr, A, S(4), M);
    hipMemsetAsync(CORR, 0, zbM, stream);
    pairs_k<64, false><<<PG, 256, 0, stream>>>(D, lst[4], CNT + 4, caps[4], Wraw[5], nullptr, nullptr, CORR);
    dense_k<4, false, true><<<gM, 256, 0, stream>>>(D, Wp[5], CORR, nullptr, nullptr, B, S(6), M);
    finalize_k<<<2, 64, 0, stream>>>(ST, 4, 6, invM);
    hipMemsetAsync(CORR, 0, zbM, stream);
    pairs_k<64, true><<<PG, 256, 0, stream>>>(A, lst[4], CNT + 4, caps[4], Wraw[6], S(4) + 128, S(4) + 192, CORR);
    dense_k<4, true, true><<<gM, 256, 0, stream>>>(A, Wp[6], CORR, S(4) + 128, S(4) + 192, C, S(5), M);
    hipMemsetAsync(CORR, 0, zbM, stream);
    pairs_k<64, true><<<PG, 256, 0, stream>>>(B, lst[3], CNT + 3, caps[3], Wraw[7], S(6) + 128, S(6) + 192, CORR);
    dense_k<4, true, true><<<gM, 256, 0, stream>>>(B, Wp[7], CORR, S(6) + 128, S(6) + 192, A, S(7), M);
    finalize_k<<<2, 64, 0, stream>>>(ST, 5, 7, invM);
    bn2_add<<<eM, 256, 0, stream>>>(C, S(5) + 128, S(5) + 192, A, S(7) + 128, S(7) + 192, B, neM);
    // X2 = B

    // ---- block 3 @ M, fin = B ----
    hipMemsetAsync(CORR, 0, zbM, stream);
    pairs_k<64, false><<<PG, 256, 0, stream>>>(B, lst[5], CNT + 5, caps[5], Wraw[8], nullptr, nullptr, CORR);
    dense_k<4, false, true><<<gM, 256, 0, stream>>>(B, Wp[8], CORR, nullptr, nullptr, A, S(8), M);
    hipMemsetAsync(CORR, 0, zbM, stream);
    pairs_k<64, false><<<PG, 256, 0, stream>>>(B, lst[6], CNT + 6, caps[6], Wraw[9], nullptr, nullptr, CORR);
    dense_k<4, false, true><<<gM, 256, 0, stream>>>(B, Wp[9], CORR, nullptr, nullptr, C, S(10), M);
    finalize_k<<<2, 64, 0, stream>>>(ST, 8, 10, invM);
    hipMemsetAsync(CORR, 0, zbM, stream);
    pairs_k<64, true><<<PG, 256, 0, stream>>>(A, lst[6], CNT + 6, caps[6], Wraw[10], S(8) + 128, S(8) + 192, CORR);
    dense_k<4, true, true><<<gM, 256, 0, stream>>>(A, Wp[10], CORR, S(8) + 128, S(8) + 192, E, S(9), M);
    hipMemsetAsync(CORR, 0, zbM, stream);
    pairs_k<64, true><<<PG, 256, 0, stream>>>(C, lst[5], CNT + 5, caps[5], Wraw[11], S(10) + 128, S(10) + 192, CORR);
    dense_k<4, true, true><<<gM, 256, 0, stream>>>(C, Wp[11], CORR, S(10) + 128, S(10) + 192, A, S(11), M);
    finalize_k<<<2, 64, 0, stream>>>(ST, 9, 11, invM);
    bn2_add<<<eM, 256, 0, stream>>>(E, S(9) + 128, S(9) + 192, A, S(11) + 128, S(11) + 192, C, neM);
    // X3 = C

    // ---- fused down: out = X1@W1 + X2@W2 + X3@W3 ----
    down_k<<<gM, 256, 0, stream>>>(D, B, C, Wp[12], Wp[13], Wp[14], (float*)d_out, M);
}

// Round 5
// 1967.026 us; speedup vs baseline: 6.9042x; 6.9042x over previous
//
#include <hip/hip_runtime.h>
#include <hip/hip_bf16.h>

#define NEG 0.01f
#define BN_EPS 1e-5f

typedef __hip_bfloat16 bf16;
typedef __attribute__((ext_vector_type(8))) short short8;
typedef __attribute__((ext_vector_type(16))) float f32x16;

// ---------------- small kernels ----------------

// stats slot: [sum(64), sumsq(64), mean(64), rstd(64)] = 256 floats
__global__ void finalize_k(float* stats, int slotA, int slotB, float inv_n) {
    int slot = (blockIdx.x == 0) ? slotA : slotB;
    float* s = stats + (size_t)slot * 256;
    int c = threadIdx.x;  // 64 threads
    float m = s[c] * inv_n;
    float v = s[64 + c] * inv_n - m * m;
    s[128 + c] = m;
    s[192 + c] = rsqrtf(v + BN_EPS);
}

// per-channel sum/sumsq of bf16 matrix (n x 64); few atomics (2 per wave)
__global__ __launch_bounds__(256) void stats_k(const bf16* __restrict__ x,
                                               float* __restrict__ stat, int n) {
    const int lane = threadIdx.x & 63;
    const int wid = blockIdx.x * (blockDim.x >> 6) + (threadIdx.x >> 6);
    const int nw = gridDim.x * (blockDim.x >> 6);
    const int rpw = (n + nw - 1) / nw;
    int r0 = wid * rpw;
    int r1 = r0 + rpw; if (r1 > n) r1 = n;
    float s = 0.f, ss = 0.f;
    for (int r = r0; r < r1; ++r) {
        float v = (float)x[(size_t)r * 64 + lane];
        s += v; ss += v * v;
    }
    atomicAdd(&stat[lane], s);
    atomicAdd(&stat[64 + lane], ss);
}

// y = leaky((x - m) * r), channel = i & 63 (in-place safe)
__global__ void bnact_k(const bf16* __restrict__ x, const float* __restrict__ m,
                        const float* __restrict__ r, bf16* __restrict__ y, int n) {
    int i = blockIdx.x * blockDim.x + threadIdx.x;
    if (i >= n) return;
    int c = i & 63;
    float v = ((float)x[i] - m[c]) * r[c];
    y[i] = __float2bfloat16(v > 0.f ? v : NEG * v);
}

// out = bnact(a) + bnact(b)
__global__ void bn2_add(const bf16* __restrict__ a, const float* __restrict__ ma,
                        const float* __restrict__ ra, const bf16* __restrict__ b,
                        const float* __restrict__ mb, const float* __restrict__ rb,
                        bf16* __restrict__ out, int n_elem) {
    int i = blockIdx.x * blockDim.x + threadIdx.x;
    if (i >= n_elem) return;
    int c = i & 63;
    float va = ((float)a[i] - ma[c]) * ra[c];
    va = va > 0.f ? va : NEG * va;
    float vb = ((float)b[i] - mb[c]) * rb[c];
    vb = vb > 0.f ? vb : NEG * vb;
    out[i] = __float2bfloat16(va + vb);
}

__global__ void cvt_f32_bf16_k(const float* __restrict__ x, bf16* __restrict__ y, int n) {
    int i = blockIdx.x * blockDim.x + threadIdx.x;
    if (i < n) y[i] = __float2bfloat16(x[i]);
}

// ---------------- weight pack ----------------
// Packed B-fragment per (tap k, K-step s, col-half c): 64 lanes x 8 bf16,
// elem j of lane l = W[k][s*16 + (l>>5)*8 + j][c*32 + (l&31)]
struct PackEnt { const float* src; bf16* dst; int kt; int ns; };
struct PackArgs { PackEnt e[16]; };

__global__ void pack_w_k(PackArgs pa) {
    PackEnt E = pa.e[blockIdx.y];
    int cin = E.ns * 16;
    int total = E.kt * E.ns * 1024;
    for (int i = blockIdx.x * blockDim.x + threadIdx.x; i < total;
         i += gridDim.x * blockDim.x) {
        int j = i & 7, lane = (i >> 3) & 63, c = (i >> 9) & 1;
        int rem = i >> 10;
        int s = rem % E.ns, k = rem / E.ns;
        int krow = s * 16 + ((lane >> 5) << 3) + j;
        int col = c * 32 + (lane & 31);
        E.dst[i] = __float2bfloat16(E.src[((size_t)k * cin + krow) * 64 + col]);
    }
}

// ---------------- fused gather-MFMA sparse conv ----------------
// One wave per 32-output-row tile, multiple tiles per wave (grid-stride).
// All tap indices loaded up-front (independent coalesced loads), ballot per
// tap (scalar-uniform), empty taps skipped. Center tap (idx==r) goes through
// the same path with a naturally coalesced gather. No atomics, no stats.
// A[m=lane&31][k=(lane>>5)*8+j]; C/D: col=lane&31, row=(i&3)+8*(i>>2)+4*(lane>>5)
template <int NS, int K>  // NS = CIN/16, K = taps (multiple of 9)
__global__ __launch_bounds__(256) void mconv2(
    const bf16* __restrict__ fin, const int* __restrict__ nbr,
    const bf16* __restrict__ Wp, bf16* __restrict__ out,
    int n_out, int n_in) {
    const int CIN = NS * 16;
    const int lane = threadIdx.x & 63;
    const int col = lane & 31;
    const int q = lane >> 5;
    const int wid = blockIdx.x * (blockDim.x >> 6) + (threadIdx.x >> 6);
    const int nw = gridDim.x * (blockDim.x >> 6);
    const int ntiles = (n_out + 31) >> 5;

    for (int tile = wid; tile < ntiles; tile += nw) {
        const int rbase = tile << 5;
        const int r = rbase + col;
        const bool rowok = r < n_out;

        f32x16 acc0, acc1;
        #pragma unroll
        for (int i = 0; i < 16; ++i) { acc0[i] = 0.f; acc1[i] = 0.f; }

        #pragma unroll
        for (int g = 0; g < K / 9; ++g) {
            // load 9 tap indices up-front (independent, coalesced)
            int idx[9];
            unsigned long long bal[9];
            #pragma unroll
            for (int t = 0; t < 9; ++t) {
                idx[t] = rowok ? nbr[(size_t)(g * 9 + t) * n_out + r] : n_in;
            }
            #pragma unroll
            for (int t = 0; t < 9; ++t) bal[t] = __ballot(idx[t] < n_in);

            #pragma unroll
            for (int t = 0; t < 9; ++t) {
                if (bal[t] == 0ull) continue;  // wave-uniform skip
                const int k = g * 9 + t;
                const bool v = idx[t] < n_in;
                const bf16* src = fin + (size_t)idx[t] * CIN + q * 8;
                short8 a[NS];
                #pragma unroll
                for (int s = 0; s < NS; ++s) {
                    if (v) a[s] = *(const short8*)(src + s * 16);
                    else { short8 z = {0,0,0,0,0,0,0,0}; a[s] = z; }
                }
                const short8* wp = (const short8*)Wp + (size_t)k * (NS * 128) + lane;
                #pragma unroll
                for (int s = 0; s < NS; ++s) {
                    short8 b0 = wp[(s * 2 + 0) * 64];
                    short8 b1 = wp[(s * 2 + 1) * 64];
                    acc0 = __builtin_amdgcn_mfma_f32_32x32x16_bf16(a[s], b0, acc0, 0, 0, 0);
                    acc1 = __builtin_amdgcn_mfma_f32_32x32x16_bf16(a[s], b1, acc1, 0, 0, 0);
                }
            }
        }

        #pragma unroll
        for (int i = 0; i < 16; ++i) {
            int row = (i & 3) + 8 * (i >> 2) + 4 * q;
            int gr = rbase + row;
            if (gr < n_out) {
                out[(size_t)gr * 64 + col] = __float2bfloat16(acc0[i]);
                out[(size_t)gr * 64 + 32 + col] = __float2bfloat16(acc1[i]);
            }
        }
    }
}

// ---------------- fused down-projection ----------------
// out(fp32) = x1@W1 + x2@W2 + x3@W3  (each 64x64, packed)
__global__ __launch_bounds__(256) void down_k(
    const bf16* __restrict__ x1, const bf16* __restrict__ x2,
    const bf16* __restrict__ x3, const bf16* __restrict__ W1,
    const bf16* __restrict__ W2, const bf16* __restrict__ W3,
    float* __restrict__ out, int m) {
    const int lane = threadIdx.x & 63;
    const int col = lane & 31;
    const int q = lane >> 5;
    const int wid = blockIdx.x * (blockDim.x >> 6) + (threadIdx.x >> 6);
    const int nw = gridDim.x * (blockDim.x >> 6);
    const int ntiles = (m + 31) >> 5;

    for (int tile = wid; tile < ntiles; tile += nw) {
        const int rbase = tile << 5;
        const int r = rbase + col;
        const bool rowok = r < m;

        f32x16 acc0, acc1;
        #pragma unroll
        for (int i = 0; i < 16; ++i) { acc0[i] = 0.f; acc1[i] = 0.f; }

        const bf16* xs[3] = {x1, x2, x3};
        const bf16* ws[3] = {W1, W2, W3};
        #pragma unroll
        for (int t = 0; t < 3; ++t) {
            const bf16* src = xs[t] + (size_t)r * 64 + q * 8;
            const short8* wp = (const short8*)ws[t] + lane;
            #pragma unroll
            for (int s = 0; s < 4; ++s) {
                short8 a;
                if (rowok) a = *(const short8*)(src + s * 16);
                else { short8 z = {0,0,0,0,0,0,0,0}; a = z; }
                short8 b0 = wp[(s * 2 + 0) * 64];
                short8 b1 = wp[(s * 2 + 1) * 64];
                acc0 = __builtin_amdgcn_mfma_f32_32x32x16_bf16(a, b0, acc0, 0, 0, 0);
                acc1 = __builtin_amdgcn_mfma_f32_32x32x16_bf16(a, b1, acc1, 0, 0, 0);
            }
        }
        #pragma unroll
        for (int i = 0; i < 16; ++i) {
            int row = (i & 3) + 8 * (i >> 2) + 4 * q;
            int gr = rbase + row;
            if (gr < m) {
                out[(size_t)gr * 64 + col] = acc0[i];
                out[(size_t)gr * 64 + 32 + col] = acc1[i];
            }
        }
    }
}

// ---------------- host ----------------

extern "C" void kernel_launch(void* const* d_in, const int* in_sizes, int n_in_,
                              void* d_out, int out_size, void* d_ws,
                              size_t ws_size, hipStream_t stream) {
    const float* feats = (const float*)d_in[0];
    // pack entries: order = b1_w1, b1_w12, b1_w2, b1_w22, pool, b2 (w1,w12,w2,w22),
    //               b3 (w1,w12,w2,w22), down x3
    const float* Wsrc[16] = {
        (const float*)d_in[1], (const float*)d_in[2],
        (const float*)d_in[3], (const float*)d_in[4],
        (const float*)d_in[5],
        (const float*)d_in[6], (const float*)d_in[7],
        (const float*)d_in[8], (const float*)d_in[9],
        (const float*)d_in[10], (const float*)d_in[11],
        (const float*)d_in[12], (const float*)d_in[13],
        (const float*)d_in[14],
        (const float*)d_in[14] + 64 * 64,
        (const float*)d_in[14] + 128 * 64,
    };
    const int kts[16] = {9,9,9,9, 27, 9,9,9,9, 9,9,9,9, 1,1,1};
    const int nss[16] = {2,4,2,4,  4, 4,4,4,4, 4,4,4,4, 4,4,4};

    const int* nA1 = (const int*)d_in[15];
    const int* nB1 = (const int*)d_in[16];
    const int* pnbr = (const int*)d_in[17];
    const int* nA2 = (const int*)d_in[18];
    const int* nB2 = (const int*)d_in[19];
    const int* nA3 = (const int*)d_in[20];
    const int* nB3 = (const int*)d_in[21];

    const int N = in_sizes[0] / 32;
    const int M = in_sizes[17] / 27;
    const size_t MX = (size_t)(N > M ? N : M);

    // ---- workspace ----
    bf16* A = (bf16*)d_ws;
    bf16* B = A + MX * 64;
    bf16* C = B + MX * 64;
    bf16* D = C + MX * 64;   // X1
    bf16* E = D + MX * 64;   // X2
    bf16* FB = E + MX * 64;  // feats bf16, N x 32
    bf16* WP = FB + (size_t)N * 32;
    bf16* Wp[16];
    {
        size_t off = 0;
        for (int i = 0; i < 16; ++i) {
            Wp[i] = WP + off;
            off += (size_t)kts[i] * nss[i] * 1024;
        }
    }
    size_t wp_total = 0;
    for (int i = 0; i < 16; ++i) wp_total += (size_t)kts[i] * nss[i] * 1024;
    float* ST = (float*)(WP + wp_total + (wp_total & 1));  // 12 slots x 256
    float* out = (float*)d_out;
    auto S = [&](int i) { return ST + (size_t)i * 256; };

    // ---- prep ----
    hipMemsetAsync(ST, 0, 12 * 256 * sizeof(float), stream);
    {
        PackArgs pa;
        for (int i = 0; i < 16; ++i) pa.e[i] = {Wsrc[i], Wp[i], kts[i], nss[i]};
        pack_w_k<<<dim3(64, 16), 256, 0, stream>>>(pa);
    }
    cvt_f32_bf16_k<<<(N * 32 + 255) / 256, 256, 0, stream>>>(feats, FB, N * 32);

    const float invN = 1.f / (float)N, invM = 1.f / (float)M;
    const int neN = N * 64, neM = M * 64;
    const int eN = (neN + 255) / 256, eM = (neM + 255) / 256;
    const int CG = 512;   // conv grid (blocks of 4 waves) -> ~4 tiles/wave at M
    const int SG = 256;   // stats grid

    // ---- block 1 @ N, C 32->64 ----
    mconv2<2, 9><<<CG, 256, 0, stream>>>(FB, nA1, Wp[0], A, N, N);
    stats_k<<<SG, 256, 0, stream>>>(A, S(0), N);
    mconv2<2, 9><<<CG, 256, 0, stream>>>(FB, nB1, Wp[2], B, N, N);
    stats_k<<<SG, 256, 0, stream>>>(B, S(2), N);
    finalize_k<<<2, 64, 0, stream>>>(ST, 0, 2, invN);
    bnact_k<<<eN, 256, 0, stream>>>(A, S(0) + 128, S(0) + 192, A, neN);
    bnact_k<<<eN, 256, 0, stream>>>(B, S(2) + 128, S(2) + 192, B, neN);
    mconv2<4, 9><<<CG, 256, 0, stream>>>(A, nB1, Wp[1], C, N, N);
    stats_k<<<SG, 256, 0, stream>>>(C, S(1), N);
    mconv2<4, 9><<<CG, 256, 0, stream>>>(B, nA1, Wp[3], A, N, N);
    stats_k<<<SG, 256, 0, stream>>>(A, S(3), N);
    finalize_k<<<2, 64, 0, stream>>>(ST, 1, 3, invN);
    bn2_add<<<eN, 256, 0, stream>>>(C, S(1) + 128, S(1) + 192,
                                    A, S(3) + 128, S(3) + 192, B, neN);
    // XP = B (N x 64)

    // ---- strided pool, K=27: B (N,64) -> D (M,64) = X1 ----
    mconv2<4, 27><<<CG, 256, 0, stream>>>(B, pnbr, Wp[4], D, M, N);

    // ---- block 2 @ M (fin = D) ----
    mconv2<4, 9><<<CG, 256, 0, stream>>>(D, nA2, Wp[5], A, M, M);
    stats_k<<<SG, 256, 0, stream>>>(A, S(4), M);
    mconv2<4, 9><<<CG, 256, 0, stream>>>(D, nB2, Wp[7], B, M, M);
    stats_k<<<SG, 256, 0, stream>>>(B, S(6), M);
    finalize_k<<<2, 64, 0, stream>>>(ST, 4, 6, invM);
    bnact_k<<<eM, 256, 0, stream>>>(A, S(4) + 128, S(4) + 192, A, neM);
    bnact_k<<<eM, 256, 0, stream>>>(B, S(6) + 128, S(6) + 192, B, neM);
    mconv2<4, 9><<<CG, 256, 0, stream>>>(A, nB2, Wp[6], C, M, M);
    stats_k<<<SG, 256, 0, stream>>>(C, S(5), M);
    mconv2<4, 9><<<CG, 256, 0, stream>>>(B, nA2, Wp[8], A, M, M);
    stats_k<<<SG, 256, 0, stream>>>(A, S(7), M);
    finalize_k<<<2, 64, 0, stream>>>(ST, 5, 7, invM);
    bn2_add<<<eM, 256, 0, stream>>>(C, S(5) + 128, S(5) + 192,
                                    A, S(7) + 128, S(7) + 192, E, neM);
    // X2 = E

    // ---- block 3 @ M (fin = E) ----
    mconv2<4, 9><<<CG, 256, 0, stream>>>(E, nA3, Wp[9], A, M, M);
    stats_k<<<SG, 256, 0, stream>>>(A, S(8), M);
    mconv2<4, 9><<<CG, 256, 0, stream>>>(E, nB3, Wp[11], B, M, M);
    stats_k<<<SG, 256, 0, stream>>>(B, S(10), M);
    finalize_k<<<2, 64, 0, stream>>>(ST, 8, 10, invM);
    bnact_k<<<eM, 256, 0, stream>>>(A, S(8) + 128, S(8) + 192, A, neM);
    bnact_k<<<eM, 256, 0, stream>>>(B, S(10) + 128, S(10) + 192, B, neM);
    mconv2<4, 9><<<CG, 256, 0, stream>>>(A, nB3, Wp[10], C, M, M);
    stats_k<<<SG, 256, 0, stream>>>(C, S(9), M);
    mconv2<4, 9><<<CG, 256, 0, stream>>>(B, nA3, Wp[12], A, M, M);
    stats_k<<<SG, 256, 0, stream>>>(A, S(11), M);
    finalize_k<<<2, 64, 0, stream>>>(ST, 9, 11, invM);
    bn2_add<<<eM, 256, 0, stream>>>(C, S(9) + 128, S(9) + 192,
                                    A, S(11) + 128, S(11) + 192, B, neM);
    // X3 = B

    // ---- fused down: out = X1@W1 + X2@W2 + X3@W3 ----
    down_k<<<CG, 256, 0, stream>>>(D, E, B, Wp[13], Wp[14], Wp[15], out, M);
}

// Round 7
// 1632.121 us; speedup vs baseline: 8.3209x; 1.2052x over previous
//
#include <hip/hip_runtime.h>
#include <hip/hip_bf16.h>

#define NEG 0.01f
#define BN_EPS 1e-5f

typedef __hip_bfloat16 bf16;
typedef __attribute__((ext_vector_type(8))) short short8;
typedef __attribute__((ext_vector_type(16))) float f32x16;

// ---------------- small kernels ----------------

// stats slot: [sum(64), sumsq(64), mean(64), rstd(64)] = 256 floats
__global__ void finalize_k(float* stats, int slotA, int slotB, float inv_n) {
    int slot = (blockIdx.x == 0) ? slotA : slotB;
    float* s = stats + (size_t)slot * 256;
    int c = threadIdx.x;  // 64 threads
    float m = s[c] * inv_n;
    float v = s[64 + c] * inv_n - m * m;
    s[128 + c] = m;
    s[192 + c] = rsqrtf(v + BN_EPS);
}

// per-channel sum/sumsq of bf16 matrix (n x 64); 2 atomics per wave
__global__ __launch_bounds__(256) void stats_k(const bf16* __restrict__ x,
                                               float* __restrict__ stat, int n) {
    const int lane = threadIdx.x & 63;
    const int wid = blockIdx.x * (blockDim.x >> 6) + (threadIdx.x >> 6);
    const int nw = gridDim.x * (blockDim.x >> 6);
    const int rpw = (n + nw - 1) / nw;
    int r0 = wid * rpw;
    int r1 = r0 + rpw; if (r1 > n) r1 = n;
    float s = 0.f, ss = 0.f;
    for (int r = r0; r < r1; ++r) {
        float v = (float)x[(size_t)r * 64 + lane];
        s += v; ss += v * v;
    }
    atomicAdd(&stat[lane], s);
    atomicAdd(&stat[64 + lane], ss);
}

// y = leaky((x - m) * r), channel = i & 63 (in-place safe)
__global__ void bnact_k(const bf16* __restrict__ x, const float* __restrict__ m,
                        const float* __restrict__ r, bf16* __restrict__ y, int n) {
    int i = blockIdx.x * blockDim.x + threadIdx.x;
    if (i >= n) return;
    int c = i & 63;
    float v = ((float)x[i] - m[c]) * r[c];
    y[i] = __float2bfloat16(v > 0.f ? v : NEG * v);
}

// out = bnact(a) + bnact(b)
__global__ void bn2_add(const bf16* __restrict__ a, const float* __restrict__ ma,
                        const float* __restrict__ ra, const bf16* __restrict__ b,
                        const float* __restrict__ mb, const float* __restrict__ rb,
                        bf16* __restrict__ out, int n_elem) {
    int i = blockIdx.x * blockDim.x + threadIdx.x;
    if (i >= n_elem) return;
    int c = i & 63;
    float va = ((float)a[i] - ma[c]) * ra[c];
    va = va > 0.f ? va : NEG * va;
    float vb = ((float)b[i] - mb[c]) * rb[c];
    vb = vb > 0.f ? vb : NEG * vb;
    out[i] = __float2bfloat16(va + vb);
}

__global__ void cvt_f32_bf16_k(const float* __restrict__ x, bf16* __restrict__ y, int n) {
    int i = blockIdx.x * blockDim.x + threadIdx.x;
    if (i < n) y[i] = __float2bfloat16(x[i]);
}

// ---------------- weight pack (32x32x16 B-fragments, proven layout) ----------
// Packed B-fragment per (tap k, K-step s, col-half c): 64 lanes x 8 bf16,
// elem j of lane l = W[k][s*16 + (l>>5)*8 + j][c*32 + (l&31)]
struct PackEnt { const float* src; bf16* dst; int kt; int ns; };
struct PackArgs { PackEnt e[16]; };

__global__ void pack_w_k(PackArgs pa) {
    PackEnt E = pa.e[blockIdx.y];
    int cin = E.ns * 16;
    int total = E.kt * E.ns * 1024;
    for (int i = blockIdx.x * blockDim.x + threadIdx.x; i < total;
         i += gridDim.x * blockDim.x) {
        int j = i & 7, lane = (i >> 3) & 63, c = (i >> 9) & 1;
        int rem = i >> 10;
        int s = rem % E.ns, k = rem / E.ns;
        int krow = s * 16 + ((lane >> 5) << 3) + j;
        int col = c * 32 + (lane & 31);
        E.dst[i] = __float2bfloat16(E.src[((size_t)k * cin + krow) * 64 + col]);
    }
}

// ---------------- fused gather-MFMA sparse conv (32-row tiles) ---------------
// One wave per 32-output-row tile (grid-stride). 32x32x16 MFMA, layouts
// verified by rounds 2/3/5: A[m=lane&31][k=(lane>>5)*8+j], B packed to match,
// C/D: col=lane&31, row=(i&3)+8*(i>>2)+4*(lane>>5).
// Register discipline: launch_bounds(256,4) caps at 128 VGPR; the tap loop is
// NOT unrolled (unroll 1) so liveness stays ~75 VGPR (round 5 hit the 256 cap
// with a fully unrolled tap loop -> 10% occupancy, 312us/conv).
template <int NS, int K>  // NS = CIN/16, K = taps (multiple of 9)
__global__ __launch_bounds__(256, 4) void mconv2(
    const bf16* __restrict__ fin, const int* __restrict__ nbr,
    const bf16* __restrict__ Wp, bf16* __restrict__ out,
    int n_out, int n_in) {
    const int CIN = NS * 16;
    const int lane = threadIdx.x & 63;
    const int col = lane & 31;
    const int q = lane >> 5;
    const int wid = blockIdx.x * (blockDim.x >> 6) + (threadIdx.x >> 6);
    const int nw = gridDim.x * (blockDim.x >> 6);
    const int ntiles = (n_out + 31) >> 5;

    for (int tile = wid; tile < ntiles; tile += nw) {
        const int rbase = tile << 5;
        const int r = rbase + col;
        const bool rowok = r < n_out;

        f32x16 acc0, acc1;
        #pragma unroll
        for (int i = 0; i < 16; ++i) { acc0[i] = 0.f; acc1[i] = 0.f; }

        #pragma unroll
        for (int g = 0; g < K / 9; ++g) {
            // 9 independent coalesced index loads up-front (memory parallelism)
            int idx[9];
            #pragma unroll
            for (int t = 0; t < 9; ++t)
                idx[t] = rowok ? nbr[(size_t)(g * 9 + t) * n_out + r] : n_in;

            #pragma unroll 1
            for (int t = 0; t < 9; ++t) {
                const bool v = idx[t] < n_in;
                if (__ballot(v) == 0ull) continue;  // wave-uniform skip
                const int k = g * 9 + t;
                const bf16* src = fin + (size_t)idx[t] * CIN + q * 8;
                const short8* wp = (const short8*)Wp + (size_t)k * (NS * 128) + lane;
                #pragma unroll
                for (int s = 0; s < NS; ++s) {
                    short8 a;
                    if (v) a = *(const short8*)(src + s * 16);
                    else { short8 z = {0,0,0,0,0,0,0,0}; a = z; }
                    short8 b0 = wp[(s * 2 + 0) * 64];
                    short8 b1 = wp[(s * 2 + 1) * 64];
                    acc0 = __builtin_amdgcn_mfma_f32_32x32x16_bf16(a, b0, acc0, 0, 0, 0);
                    acc1 = __builtin_amdgcn_mfma_f32_32x32x16_bf16(a, b1, acc1, 0, 0, 0);
                }
            }
        }

        #pragma unroll
        for (int i = 0; i < 16; ++i) {
            int row = (i & 3) + 8 * (i >> 2) + 4 * q;
            int gr = rbase + row;
            if (gr < n_out) {
                out[(size_t)gr * 64 + col] = __float2bfloat16(acc0[i]);
                out[(size_t)gr * 64 + 32 + col] = __float2bfloat16(acc1[i]);
            }
        }
    }
}

// ---------------- fused down-projection ----------------
// out(fp32) = x1@W1 + x2@W2 + x3@W3  (each 64x64, packed)
__global__ __launch_bounds__(256, 4) void down_k(
    const bf16* __restrict__ x1, const bf16* __restrict__ x2,
    const bf16* __restrict__ x3, const bf16* __restrict__ W1,
    const bf16* __restrict__ W2, const bf16* __restrict__ W3,
    float* __restrict__ out, int m) {
    const int lane = threadIdx.x & 63;
    const int col = lane & 31;
    const int q = lane >> 5;
    const int wid = blockIdx.x * (blockDim.x >> 6) + (threadIdx.x >> 6);
    const int nw = gridDim.x * (blockDim.x >> 6);
    const int ntiles = (m + 31) >> 5;

    for (int tile = wid; tile < ntiles; tile += nw) {
        const int rbase = tile << 5;
        const int r = rbase + col;
        const bool rowok = r < m;

        f32x16 acc0, acc1;
        #pragma unroll
        for (int i = 0; i < 16; ++i) { acc0[i] = 0.f; acc1[i] = 0.f; }

        const bf16* xs[3] = {x1, x2, x3};
        const bf16* ws[3] = {W1, W2, W3};
        #pragma unroll 1
        for (int t = 0; t < 3; ++t) {
            const bf16* src = xs[t] + (size_t)r * 64 + q * 8;
            const short8* wp = (const short8*)ws[t] + lane;
            #pragma unroll
            for (int s = 0; s < 4; ++s) {
                short8 a;
                if (rowok) a = *(const short8*)(src + s * 16);
                else { short8 z = {0,0,0,0,0,0,0,0}; a = z; }
                short8 b0 = wp[(s * 2 + 0) * 64];
                short8 b1 = wp[(s * 2 + 1) * 64];
                acc0 = __builtin_amdgcn_mfma_f32_32x32x16_bf16(a, b0, acc0, 0, 0, 0);
                acc1 = __builtin_amdgcn_mfma_f32_32x32x16_bf16(a, b1, acc1, 0, 0, 0);
            }
        }
        #pragma unroll
        for (int i = 0; i < 16; ++i) {
            int row = (i & 3) + 8 * (i >> 2) + 4 * q;
            int gr = rbase + row;
            if (gr < m) {
                out[(size_t)gr * 64 + col] = acc0[i];
                out[(size_t)gr * 64 + 32 + col] = acc1[i];
            }
        }
    }
}

// ---------------- host ----------------

extern "C" void kernel_launch(void* const* d_in, const int* in_sizes, int n_in_,
                              void* d_out, int out_size, void* d_ws,
                              size_t ws_size, hipStream_t stream) {
    const float* feats = (const float*)d_in[0];
    const float* Wsrc[16] = {
        (const float*)d_in[1], (const float*)d_in[2],
        (const float*)d_in[3], (const float*)d_in[4],
        (const float*)d_in[5],
        (const float*)d_in[6], (const float*)d_in[7],
        (const float*)d_in[8], (const float*)d_in[9],
        (const float*)d_in[10], (const float*)d_in[11],
        (const float*)d_in[12], (const float*)d_in[13],
        (const float*)d_in[14],
        (const float*)d_in[14] + 64 * 64,
        (const float*)d_in[14] + 128 * 64,
    };
    const int kts[16] = {9,9,9,9, 27, 9,9,9,9, 9,9,9,9, 1,1,1};
    const int nss[16] = {2,4,2,4,  4, 4,4,4,4, 4,4,4,4, 4,4,4};

    const int* nA1 = (const int*)d_in[15];
    const int* nB1 = (const int*)d_in[16];
    const int* pnbr = (const int*)d_in[17];
    const int* nA2 = (const int*)d_in[18];
    const int* nB2 = (const int*)d_in[19];
    const int* nA3 = (const int*)d_in[20];
    const int* nB3 = (const int*)d_in[21];

    const int N = in_sizes[0] / 32;
    const int M = in_sizes[17] / 27;
    const size_t MX = (size_t)(N > M ? N : M);

    // ---- workspace ----
    bf16* A = (bf16*)d_ws;
    bf16* B = A + MX * 64;
    bf16* C = B + MX * 64;
    bf16* D = C + MX * 64;   // X1
    bf16* E = D + MX * 64;   // X2
    bf16* FB = E + MX * 64;  // feats bf16, N x 32
    bf16* WP = FB + (size_t)N * 32;
    bf16* Wp[16];
    {
        size_t off = 0;
        for (int i = 0; i < 16; ++i) {
            Wp[i] = WP + off;
            off += (size_t)kts[i] * nss[i] * 1024;
        }
    }
    size_t wp_total = 0;
    for (int i = 0; i < 16; ++i) wp_total += (size_t)kts[i] * nss[i] * 1024;
    float* ST = (float*)(WP + wp_total + (wp_total & 1));  // 12 slots x 256
    float* out = (float*)d_out;
    auto S = [&](int i) { return ST + (size_t)i * 256; };

    // ---- prep ----
    hipMemsetAsync(ST, 0, 12 * 256 * sizeof(float), stream);
    {
        PackArgs pa;
        for (int i = 0; i < 16; ++i) pa.e[i] = {Wsrc[i], Wp[i], kts[i], nss[i]};
        pack_w_k<<<dim3(64, 16), 256, 0, stream>>>(pa);
    }
    cvt_f32_bf16_k<<<(N * 32 + 255) / 256, 256, 0, stream>>>(feats, FB, N * 32);

    const float invN = 1.f / (float)N, invM = 1.f / (float)M;
    const int neN = N * 64, neM = M * 64;
    const int eN = (neN + 255) / 256, eM = (neM + 255) / 256;
    const int CG = 1024;  // 4096 waves == exactly full residency at 4 waves/EU
    const int SG = 256;   // stats grid

    // ---- block 1 @ N, C 32->64 ----
    mconv2<2, 9><<<CG, 256, 0, stream>>>(FB, nA1, Wp[0], A, N, N);
    stats_k<<<SG, 256, 0, stream>>>(A, S(0), N);
    mconv2<2, 9><<<CG, 256, 0, stream>>>(FB, nB1, Wp[2], B, N, N);
    stats_k<<<SG, 256, 0, stream>>>(B, S(2), N);
    finalize_k<<<2, 64, 0, stream>>>(ST, 0, 2, invN);
    bnact_k<<<eN, 256, 0, stream>>>(A, S(0) + 128, S(0) + 192, A, neN);
    bnact_k<<<eN, 256, 0, stream>>>(B, S(2) + 128, S(2) + 192, B, neN);
    mconv2<4, 9><<<CG, 256, 0, stream>>>(A, nB1, Wp[1], C, N, N);
    stats_k<<<SG, 256, 0, stream>>>(C, S(1), N);
    mconv2<4, 9><<<CG, 256, 0, stream>>>(B, nA1, Wp[3], A, N, N);
    stats_k<<<SG, 256, 0, stream>>>(A, S(3), N);
    finalize_k<<<2, 64, 0, stream>>>(ST, 1, 3, invN);
    bn2_add<<<eN, 256, 0, stream>>>(C, S(1) + 128, S(1) + 192,
                                    A, S(3) + 128, S(3) + 192, B, neN);
    // XP = B (N x 64)

    // ---- strided pool, K=27: B (N,64) -> D (M,64) = X1 ----
    mconv2<4, 27><<<CG, 256, 0, stream>>>(B, pnbr, Wp[4], D, M, N);

    // ---- block 2 @ M (fin = D) ----
    mconv2<4, 9><<<CG, 256, 0, stream>>>(D, nA2, Wp[5], A, M, M);
    stats_k<<<SG, 256, 0, stream>>>(A, S(4), M);
    mconv2<4, 9><<<CG, 256, 0, stream>>>(D, nB2, Wp[7], B, M, M);
    stats_k<<<SG, 256, 0, stream>>>(B, S(6), M);
    finalize_k<<<2, 64, 0, stream>>>(ST, 4, 6, invM);
    bnact_k<<<eM, 256, 0, stream>>>(A, S(4) + 128, S(4) + 192, A, neM);
    bnact_k<<<eM, 256, 0, stream>>>(B, S(6) + 128, S(6) + 192, B, neM);
    mconv2<4, 9><<<CG, 256, 0, stream>>>(A, nB2, Wp[6], C, M, M);
    stats_k<<<SG, 256, 0, stream>>>(C, S(5), M);
    mconv2<4, 9><<<CG, 256, 0, stream>>>(B, nA2, Wp[8], A, M, M);
    stats_k<<<SG, 256, 0, stream>>>(A, S(7), M);
    finalize_k<<<2, 64, 0, stream>>>(ST, 5, 7, invM);
    bn2_add<<<eM, 256, 0, stream>>>(C, S(5) + 128, S(5) + 192,
                                    A, S(7) + 128, S(7) + 192, E, neM);
    // X2 = E

    // ---- block 3 @ M (fin = E) ----
    mconv2<4, 9><<<CG, 256, 0, stream>>>(E, nA3, Wp[9], A, M, M);
    stats_k<<<SG, 256, 0, stream>>>(A, S(8), M);
    mconv2<4, 9><<<CG, 256, 0, stream>>>(E, nB3, Wp[11], B, M, M);
    stats_k<<<SG, 256, 0, stream>>>(B, S(10), M);
    finalize_k<<<2, 64, 0, stream>>>(ST, 8, 10, invM);
    bnact_k<<<eM, 256, 0, stream>>>(A, S(8) + 128, S(8) + 192, A, neM);
    bnact_k<<<eM, 256, 0, stream>>>(B, S(10) + 128, S(10) + 192, B, neM);
    mconv2<4, 9><<<CG, 256, 0, stream>>>(A, nB3, Wp[10], C, M, M);
    stats_k<<<SG, 256, 0, stream>>>(C, S(9), M);
    mconv2<4, 9><<<CG, 256, 0, stream>>>(B, nA3, Wp[12], A, M, M);
    stats_k<<<SG, 256, 0, stream>>>(A, S(11), M);
    finalize_k<<<2, 64, 0, stream>>>(ST, 9, 11, invM);
    bn2_add<<<eM, 256, 0, stream>>>(C, S(9) + 128, S(9) + 192,
                                    A, S(11) + 128, S(11) + 192, B, neM);
    // X3 = B

    // ---- fused down: out = X1@W1 + X2@W2 + X3@W3 ----
    down_k<<<CG, 256, 0, stream>>>(D, E, B, Wp[13], Wp[14], Wp[15], out, M);
}